// Round 2
// baseline (616.342 us; speedup 1.0000x reference)
//
#include <hip/hip_runtime.h>

// GAE backward scan: B=8192 rows, S=2048 steps, fp32.
// One wave (64 lanes) per row; each lane owns 32 contiguous timesteps.
// Segmented parallel scan of the affine recurrence g_t = a_t*g_{t+1} + b_t.
//
// R2: a[k] = GL*m*(1-d) takes only values {0, GL} -> stored as a 32-bit
// bitmask instead of a 32-float array, cutting per-lane state from 96 to
// 64 floats so everything fits in VGPRs (R1 showed 88 VGPRs for 96-float
// state => scratch spill => latency-bound at 3x the memory floor).

static constexpr int BATCH = 8192;
static constexpr int SEQ   = 2048;
static constexpr int CHUNK = SEQ / 64;          // 32 elements per lane
static constexpr float GAMMA  = 0.999f;
static constexpr float LAMBDA = 0.95f;
static constexpr float GL     = GAMMA * LAMBDA; // 0.94905f

__global__ __launch_bounds__(256, 2) void gae_kernel(
    const float* __restrict__ rewards,
    const float* __restrict__ values,
    const int*   __restrict__ dones,
    const int*   __restrict__ mask,
    float*       __restrict__ out)   // [2*B*S]: advantages then returns
{
    const int lane = threadIdx.x & 63;
    const int row  = blockIdx.x * (blockDim.x >> 6) + (threadIdx.x >> 6);
    if (row >= BATCH) return;

    const size_t base = (size_t)row * SEQ + (size_t)lane * CHUNK;

    // Per-lane register state: b of the affine map, masked values, and the
    // a-coefficient as one bit per timestep (set => a = GL, clear => a = 0).
    float b[CHUNK], vmm[CHUNK];
    unsigned int abits = 0;

    const float4* rp = reinterpret_cast<const float4*>(rewards + base);
    const float4* vp = reinterpret_cast<const float4*>(values  + base);
    const int4*   dp = reinterpret_cast<const int4*>(dones + base);
    const int4*   mp = reinterpret_cast<const int4*>(mask  + base);

    // b[k] needs vmm[k+1]; compute b one element late via pending scalars.
    float pend_mr = 0.f, pend_mnd = 0.f, pend_vmm = 0.f;

    #pragma unroll
    for (int q = 0; q < CHUNK / 4; ++q) {
        float4 r4 = rp[q];
        float4 v4 = vp[q];
        int4   d4 = dp[q];
        int4   m4 = mp[q];
        float rr[4] = {r4.x, r4.y, r4.z, r4.w};
        float vv[4] = {v4.x, v4.y, v4.z, v4.w};
        int   dd[4] = {d4.x, d4.y, d4.z, d4.w};
        int   mm[4] = {m4.x, m4.y, m4.z, m4.w};
        #pragma unroll
        for (int j = 0; j < 4; ++j) {
            const int k = 4 * q + j;
            const bool m  = (mm[j] != 0);
            const bool mn = m && (dd[j] == 0);       // m * (1 - done)
            abits |= (mn ? (1u << k) : 0u);
            const float vm = m ? vv[j] : 0.0f;
            vmm[k] = vm;
            if (k > 0) {
                // b[k-1] = m*r + GAMMA*(m_{k}*v_{k})*(m*(1-d)) - m*v
                b[k - 1] = pend_mr + GAMMA * vm * pend_mnd - pend_vmm;
            }
            pend_mr  = m ? rr[j] : 0.0f;
            pend_mnd = mn ? 1.0f : 0.0f;
            pend_vmm = vm;
        }
    }
    // Last element of this lane's chunk: next value is the NEXT lane's vmm[0];
    // lane 63 owns t=S-1 whose next value is 0.
    float nv_edge = __shfl_down(vmm[0], 1, 64);
    if (lane == 63) nv_edge = 0.0f;
    b[CHUNK - 1] = pend_mr + GAMMA * nv_edge * pend_mnd - pend_vmm;

    // Local (reverse-time) composition over this lane's chunk:
    // F = f_{t0} ∘ ... ∘ f_{t0+CHUNK-1}, F(g) = A*g + B.
    float A = 1.0f, Bc = 0.0f;
    #pragma unroll
    for (int k = CHUNK - 1; k >= 0; --k) {
        const float ak = (abits & (1u << k)) ? GL : 0.0f;
        Bc = fmaf(ak, Bc, b[k]);
        A  = ak * A;
    }

    // Wave-level inclusive suffix scan of compositions (lane i ends with
    // composition over lanes [i, 64)). Combine: F_i = F_i ∘ F_{i+d}.
    #pragma unroll
    for (int d = 1; d < 64; d <<= 1) {
        float Ao = __shfl_down(A,  d, 64);
        float Bo = __shfl_down(Bc, d, 64);
        if (lane + d < 64) {
            Bc = fmaf(A, Bo, Bc);
            A  = A * Ao;
        }
    }
    // Carry entering this lane's chunk = suffix over lanes (i, 64) applied to
    // g_S = 0, i.e. the B of lane i+1's scan result. Lane 63 carries 0.
    float carry = __shfl_down(Bc, 1, 64);
    if (lane == 63) carry = 0.0f;

    // Apply recurrence; overwrite b[] with advantages, vmm[] with returns.
    float g = carry;
    #pragma unroll
    for (int k = CHUNK - 1; k >= 0; --k) {
        const float ak = (abits & (1u << k)) ? GL : 0.0f;
        g = fmaf(ak, g, b[k]);
        b[k]   = g;            // advantage (already 0 outside valid prefix)
        vmm[k] = vmm[k] + g;   // return = g + mask*v (0 outside prefix)
    }

    float4* ap = reinterpret_cast<float4*>(out + base);
    float4* tp = reinterpret_cast<float4*>(out + (size_t)BATCH * SEQ + base);
    #pragma unroll
    for (int q = 0; q < CHUNK / 4; ++q) {
        ap[q] = make_float4(b[4*q+0],   b[4*q+1],   b[4*q+2],   b[4*q+3]);
        tp[q] = make_float4(vmm[4*q+0], vmm[4*q+1], vmm[4*q+2], vmm[4*q+3]);
    }
}

extern "C" void kernel_launch(void* const* d_in, const int* in_sizes, int n_in,
                              void* d_out, int out_size, void* d_ws, size_t ws_size,
                              hipStream_t stream) {
    const float* rewards = (const float*)d_in[0];
    const float* values  = (const float*)d_in[1];
    const int*   dones   = (const int*)d_in[2];
    const int*   mask    = (const int*)d_in[3];
    float* out = (float*)d_out;

    const int rows_per_block = 256 / 64;                 // 4 waves -> 4 rows
    dim3 grid(BATCH / rows_per_block), block(256);
    gae_kernel<<<grid, block, 0, stream>>>(rewards, values, dones, mask, out);
}

// Round 3
// 320.291 us; speedup vs baseline: 1.9243x; 1.9243x over previous
//
#include <hip/hip_runtime.h>

// GAE backward scan: B=8192 rows, S=2048 steps, fp32.
// R3 redesign: one wave per row, time processed as 8 sequential blocks of
// 256 steps (reverse). Lane l owns 4 contiguous steps per block -> float4
// fully-coalesced loads/stores. Per-lane live state is ~15 scalars: no
// register-array spill by construction (R1/R2 spilled 32-float arrays to
// scratch; R2's scratch blew L2 -> 1.3 GB HBM fetch).

static constexpr int BATCH = 8192;
static constexpr int SEQ   = 2048;
static constexpr int TBLK  = 256;               // timesteps per block-iteration
static constexpr int NBLK  = SEQ / TBLK;        // 8
static constexpr float GAMMA  = 0.999f;
static constexpr float LAMBDA = 0.95f;
static constexpr float GL     = GAMMA * LAMBDA;

__global__ __launch_bounds__(256, 4) void gae_kernel(
    const float* __restrict__ rewards,
    const float* __restrict__ values,
    const int*   __restrict__ dones,
    const int*   __restrict__ mask,
    float*       __restrict__ out)   // [2*B*S]: advantages then returns
{
    const int lane = threadIdx.x & 63;
    const int row  = blockIdx.x * 4 + (threadIdx.x >> 6);
    const size_t rowbase = (size_t)row * SEQ;

    float C    = 0.0f;   // g entering the current block from the future
    float edge = 0.0f;   // masked value at t = (block end), i.e. vmm[0] of the later block

    for (int j = NBLK - 1; j >= 0; --j) {
        const size_t off = rowbase + (size_t)j * TBLK + (size_t)lane * 4;

        const float4 r4 = *reinterpret_cast<const float4*>(rewards + off);
        const float4 v4 = *reinterpret_cast<const float4*>(values  + off);
        const int4   d4 = *reinterpret_cast<const int4*>(dones + off);
        const int4   m4 = *reinterpret_cast<const int4*>(mask  + off);

        const float rr[4] = {r4.x, r4.y, r4.z, r4.w};
        const float vv[4] = {v4.x, v4.y, v4.z, v4.w};
        const int   dd[4] = {d4.x, d4.y, d4.z, d4.w};
        const int   mm[4] = {m4.x, m4.y, m4.z, m4.w};

        float a[4], b[4], vm[4];
        float mr[4], mnd[4];
        #pragma unroll
        for (int e = 0; e < 4; ++e) {
            const bool m  = (mm[e] != 0);
            const bool mn = m && (dd[e] == 0);
            vm[e]  = m ? vv[e] : 0.0f;
            mr[e]  = m ? rr[e] : 0.0f;
            mnd[e] = mn ? 1.0f : 0.0f;
            a[e]   = mn ? GL : 0.0f;
        }
        // next (masked) value for each element
        float nv3 = __shfl_down(vm[0], 1, 64);   // next lane's first element
        if (lane == 63) nv3 = edge;              // later block's first element (0 for j=7)
        const float nv[4] = {vm[1], vm[2], vm[3], nv3};
        #pragma unroll
        for (int e = 0; e < 4; ++e)
            b[e] = mr[e] + GAMMA * nv[e] * mnd[e] - vm[e];

        // Local reverse-time composition over this lane's 4 elements.
        float A = a[3], B = b[3];
        #pragma unroll
        for (int e = 2; e >= 0; --e) {
            B = fmaf(a[e], B, b[e]);
            A = a[e] * A;
        }

        // Wave inclusive suffix scan of compositions: lane l ends holding the
        // composition over lanes [l, 63].  (outer ∘ inner): B = A*B' + B, A = A*A'.
        float As = A, Bs = B;
        #pragma unroll
        for (int d = 1; d < 64; d <<= 1) {
            const float Ao = __shfl_down(As, d, 64);
            const float Bo = __shfl_down(Bs, d, 64);
            if (lane + d < 64) {
                Bs = fmaf(As, Bo, Bs);
                As = As * Ao;
            }
        }
        // Whole-block composition (lane 0's inclusive result) for the carry chain.
        const float A0 = __shfl(As, 0, 64);
        const float B0 = __shfl(Bs, 0, 64);
        // Carry entering this lane's chunk = lane (l+1)'s inclusive result applied to C.
        float cA = __shfl_down(As, 1, 64);
        float cB = __shfl_down(Bs, 1, 64);
        if (lane == 63) { cA = 1.0f; cB = 0.0f; }
        float g = fmaf(cA, C, cB);

        // Apply recurrence locally (element 3 is latest in time).
        float adv[4], ret[4];
        #pragma unroll
        for (int e = 3; e >= 0; --e) {
            g = fmaf(a[e], g, b[e]);
            adv[e] = g;
            ret[e] = g + vm[e];
        }

        // Serial cross-block state for the next (earlier) block.
        C    = fmaf(A0, C, B0);
        edge = __shfl(vm[0], 0, 64);

        *reinterpret_cast<float4*>(out + off) =
            make_float4(adv[0], adv[1], adv[2], adv[3]);
        *reinterpret_cast<float4*>(out + (size_t)BATCH * SEQ + off) =
            make_float4(ret[0], ret[1], ret[2], ret[3]);
    }
}

extern "C" void kernel_launch(void* const* d_in, const int* in_sizes, int n_in,
                              void* d_out, int out_size, void* d_ws, size_t ws_size,
                              hipStream_t stream) {
    const float* rewards = (const float*)d_in[0];
    const float* values  = (const float*)d_in[1];
    const int*   dones   = (const int*)d_in[2];
    const int*   mask    = (const int*)d_in[3];
    float* out = (float*)d_out;

    dim3 grid(BATCH / 4), block(256);   // 4 waves/block, one row per wave
    gae_kernel<<<grid, block, 0, stream>>>(rewards, values, dones, mask, out);
}